// Round 5
// baseline (1549.358 us; speedup 1.0000x reference)
//
#include <hip/hip_runtime.h>
#include <hip/hip_bf16.h>

#define HWSZ (192*192)

typedef __attribute__((ext_vector_type(8))) short short8v;
typedef __attribute__((ext_vector_type(4))) float f32x4;

// prep'd weight element counts
#define WG_N  331776   // conv w: [tap][oc][c]  9*192*192
#define WQ2_N 110592   // qkv  w: [576][192] straight cast
#define PW2_N 36864    // proj w: [192][192] straight cast
#define W1_N  73728    // glu  w: [384][192] straight cast
#define WBYTES ((size_t)2*(WG_N+WQ2_N+PW2_N+W1_N))   // 1,105,920

// ---------------------------------------------------------------------------
// prep: cast/reorder weights to bf16
// ---------------------------------------------------------------------------
__global__ __launch_bounds__(256)
void prep_weights(const float* __restrict__ w2_w, const float* __restrict__ qkv_w,
                  const float* __restrict__ proj_w, const float* __restrict__ w1_w,
                  __hip_bfloat16* __restrict__ wg, __hip_bfloat16* __restrict__ wq,
                  __hip_bfloat16* __restrict__ pw, __hip_bfloat16* __restrict__ w1b)
{
    int i = blockIdx.x*256 + threadIdx.x;
    if (i < WG_N) {
        int tap = i / 36864; int r = i - tap*36864;
        int oc = r / 192;    int c = r - oc*192;
        wg[i] = __float2bfloat16(w2_w[((size_t)oc*192 + c)*9 + tap]);
    } else if (i < WG_N + WQ2_N) {
        int j = i - WG_N;  wq[j] = __float2bfloat16(qkv_w[j]);
    } else if (i < WG_N + WQ2_N + PW2_N) {
        int j = i - WG_N - WQ2_N;  pw[j] = __float2bfloat16(proj_w[j]);
    } else if (i < WG_N + WQ2_N + PW2_N + W1_N) {
        int j = i - WG_N - WQ2_N - PW2_N;  w1b[j] = __float2bfloat16(w1_w[j]);
    }
}

// ---------------------------------------------------------------------------
// K1a: QKV GEMM per window. Wave = head (144 rows = 9 m-tiles).
// Writes q,k as [win][h][t][48] (direct stores); v as [win][h][d][t] via
// per-wave LDS transpose. Fragment convention (HW-verified R2/R3):
//   A/B: lane&15 = non-K idx, k=(lane>>4)*8+0..7 contiguous; D: row=(lane>>4)*4+r, col=lane&15
// ---------------------------------------------------------------------------
__global__ __launch_bounds__(256, 4)
void qkv_kernel(const float* __restrict__ x, const __hip_bfloat16* __restrict__ wq,
                const float* __restrict__ qkv_b,
                __hip_bfloat16* __restrict__ q_ws, __hip_bfloat16* __restrict__ k_ws,
                __hip_bfloat16* __restrict__ v_ws, int win0)
{
    __shared__ __align__(16) __hip_bfloat16 Xs[64][200];
    __shared__ __align__(16) __hip_bfloat16 vstg[4][16][72];

    const int tid = threadIdx.x;
    const int qw  = blockIdx.x;
    const int wid = win0 + qw;
    const int b   = wid / 576;
    const int wr  = wid - b*576;
    const int wi  = wr / 24;
    const int wj  = wr - wi*24;

    const float* xb = x + (size_t)b*192*HWSZ + (size_t)(wi*8)*192 + wj*8;
    for (int idx = tid; idx < 12288; idx += 256) {
        int c = idx >> 6, t = idx & 63;
        Xs[t][c] = __float2bfloat16(xb[(size_t)c*HWSZ + (t>>3)*192 + (t&7)]);
    }
    __syncthreads();

    const int lane = tid & 63;
    const int h    = tid >> 6;     // wave = head
    const int lx   = lane & 15;
    const int kg   = lane >> 4;

    const size_t qkbase = (size_t)(qw*4 + h)*64*48;
    const size_t vbase  = (size_t)(qw*4 + h)*48*64;

    #pragma unroll 1
    for (int reg = 0; reg < 3; ++reg) {          // 0=q, 1=k, 2=v
        const int jrow0 = reg*192 + h*48;
        f32x4 qa[3][4];
        #pragma unroll
        for (int m=0;m<3;m++)
            #pragma unroll
            for (int n=0;n<4;n++) qa[m][n] = (f32x4){0.f,0.f,0.f,0.f};

        #pragma unroll
        for (int kc=0; kc<6; ++kc) {
            short8v bf[4];
            #pragma unroll
            for (int n=0;n<4;n++)
                bf[n] = *(const short8v*)&Xs[n*16+lx][kc*32+kg*8];
            #pragma unroll
            for (int mm=0; mm<3; ++mm) {
                short8v af = *(const short8v*)
                    &wq[(size_t)(jrow0 + mm*16 + lx)*192 + kc*32 + kg*8];
                #pragma unroll
                for (int n=0;n<4;n++)
                    qa[mm][n] = __builtin_amdgcn_mfma_f32_16x16x32_bf16(
                                    af, bf[n], qa[mm][n], 0,0,0);
            }
        }

        if (reg < 2) {
            __hip_bfloat16* dst = (reg==0 ? q_ws : k_ws) + qkbase;
            #pragma unroll
            for (int mm=0; mm<3; ++mm) {
                const int dd0 = mm*16 + kg*4;
                float b4[4];
                #pragma unroll
                for (int r=0;r<4;r++) b4[r] = qkv_b[jrow0 + dd0 + r];
                #pragma unroll
                for (int n=0;n<4;n++) {
                    const int t = n*16 + lx;
                    union { ushort4 u; __hip_bfloat16 e[4]; } pk;
                    #pragma unroll
                    for (int r=0;r<4;r++)
                        pk.e[r] = __float2bfloat16(qa[mm][n][r] + b4[r]);
                    *(ushort4*)&dst[(size_t)t*48 + dd0] = pk.u;
                }
            }
        } else {
            // v: transpose each 16x64 tile through LDS -> [d][t]
            #pragma unroll 1
            for (int mm=0; mm<3; ++mm) {
                const int dd0 = mm*16;
                float b4[4];
                #pragma unroll
                for (int r=0;r<4;r++) b4[r] = qkv_b[jrow0 + dd0 + kg*4 + r];
                #pragma unroll
                for (int n=0;n<4;n++)
                    #pragma unroll
                    for (int r=0;r<4;r++)
                        vstg[h][kg*4+r][n*16+lx] = __float2bfloat16(qa[mm][n][r] + b4[r]);
                // same-wave copy out (in-order LDS, no barrier needed)
                const int rr  = lane >> 2;
                const int tq0 = (lane & 3)*16;
                #pragma unroll
                for (int qq=0; qq<4; ++qq)
                    *(ushort4*)&v_ws[vbase + (size_t)(dd0+rr)*64 + tq0 + qq*4] =
                        *(const ushort4*)&vstg[h][rr][tq0 + qq*4];
            }
        }
    }
}

// ---------------------------------------------------------------------------
// K1b: attention core. Wave = window; 4 windows/block. q,k,v from ws (global),
// p through per-wave LDS; o [win][t][h*48+dd] out via LDS transpose (overlay p).
// K=48 handled as one K=32 MFMA + one half-zero-fragment K=32 MFMA.
// ---------------------------------------------------------------------------
__global__ __launch_bounds__(256, 3)
void attn_core(const __hip_bfloat16* __restrict__ q_ws,
               const __hip_bfloat16* __restrict__ k_ws,
               const __hip_bfloat16* __restrict__ v_ws,
               const float* __restrict__ bias_tab,
               __hip_bfloat16* __restrict__ o_ws)
{
    __shared__ __align__(16) __hip_bfloat16 p_lds[4][64][72];
    __shared__ __align__(16) __hip_bfloat16 bias_bf[64][66];

    const int tid = threadIdx.x;
    for (int i = tid; i < 4096; i += 256) {
        int tq = i >> 6, tk = i & 63;
        int dy = (tq>>3) - (tk>>3) + 7;
        int dx = (tq&7)  - (tk&7)  + 7;
        bias_bf[tq][tk] = __float2bfloat16(bias_tab[dy*15 + dx]);
    }
    __syncthreads();

    const int lane = tid & 63;
    const int wv   = tid >> 6;
    const int lx   = lane & 15;
    const int kg   = lane >> 4;
    const int qw   = blockIdx.x*4 + wv;

    __hip_bfloat16* pl = &p_lds[wv][0][0];
    const float scale = 0.14433756729740643f; // 1/sqrt(48)
    const short8v z8 = {0,0,0,0,0,0,0,0};

    #pragma unroll 1
    for (int h=0; h<4; ++h) {
        const size_t qkb = (size_t)(qw*4 + h)*64*48;
        const size_t vb  = (size_t)(qw*4 + h)*48*64;

        // ---- scores ----
        f32x4 sa[4][4];
        #pragma unroll
        for (int m=0;m<4;m++)
            #pragma unroll
            for (int n=0;n<4;n++) sa[m][n] = (f32x4){0.f,0.f,0.f,0.f};

        {   // kc0: d 0..31
            short8v bk[4];
            #pragma unroll
            for (int n=0;n<4;n++)
                bk[n] = *(const short8v*)&k_ws[qkb + (size_t)(n*16+lx)*48 + kg*8];
            #pragma unroll
            for (int m=0;m<4;m++) {
                short8v aq = *(const short8v*)&q_ws[qkb + (size_t)(m*16+lx)*48 + kg*8];
                #pragma unroll
                for (int n=0;n<4;n++)
                    sa[m][n] = __builtin_amdgcn_mfma_f32_16x16x32_bf16(aq, bk[n], sa[m][n],0,0,0);
            }
        }
        {   // kc1: d 32..47 in k-slots 0..15 (kg<2), zeros elsewhere
            short8v bk[4];
            #pragma unroll
            for (int n=0;n<4;n++) {
                short8v f = z8;
                if (kg < 2) f = *(const short8v*)&k_ws[qkb + (size_t)(n*16+lx)*48 + 32 + kg*8];
                bk[n] = f;
            }
            #pragma unroll
            for (int m=0;m<4;m++) {
                short8v aq = z8;
                if (kg < 2) aq = *(const short8v*)&q_ws[qkb + (size_t)(m*16+lx)*48 + 32 + kg*8];
                #pragma unroll
                for (int n=0;n<4;n++)
                    sa[m][n] = __builtin_amdgcn_mfma_f32_16x16x32_bf16(aq, bk[n], sa[m][n],0,0,0);
            }
        }

        // ---- softmax (rows in 16-lane groups) -> p_lds ----
        #pragma unroll
        for (int m=0;m<4;m++) {
            #pragma unroll
            for (int r=0;r<4;r++) {
                const int trow = m*16 + kg*4 + r;
                float s[4];
                float mx = -1e30f;
                #pragma unroll
                for (int n=0;n<4;n++){
                    s[n] = sa[m][n][r]*scale + __bfloat162float(bias_bf[trow][n*16+lx]);
                    mx = fmaxf(mx, s[n]);
                }
                mx = fmaxf(mx, __shfl_xor(mx,1));
                mx = fmaxf(mx, __shfl_xor(mx,2));
                mx = fmaxf(mx, __shfl_xor(mx,4));
                mx = fmaxf(mx, __shfl_xor(mx,8));
                float l = 0.f;
                #pragma unroll
                for (int n=0;n<4;n++){ s[n] = __expf(s[n]-mx); l += s[n]; }
                l += __shfl_xor(l,1); l += __shfl_xor(l,2);
                l += __shfl_xor(l,4); l += __shfl_xor(l,8);
                const float inv = 1.f/l;
                #pragma unroll
                for (int n=0;n<4;n++)
                    pl[trow*72 + n*16+lx] = __float2bfloat16(s[n]*inv);
            }
        }

        // ---- PV: O[tq][d], A=p, B=v, K=64 ----
        f32x4 oa[4][3];
        #pragma unroll
        for (int m=0;m<4;m++)
            #pragma unroll
            for (int n=0;n<3;n++) oa[m][n] = (f32x4){0.f,0.f,0.f,0.f};
        #pragma unroll
        for (int kc=0; kc<2; ++kc) {
            short8v bvv[3];
            #pragma unroll
            for (int n=0;n<3;n++)
                bvv[n] = *(const short8v*)&v_ws[vb + (size_t)(n*16+lx)*64 + kc*32 + kg*8];
            #pragma unroll
            for (int m=0;m<4;m++) {
                short8v ap = *(const short8v*)&pl[(m*16+lx)*72 + kc*32 + kg*8];
                #pragma unroll
                for (int n=0;n<3;n++)
                    oa[m][n] = __builtin_amdgcn_mfma_f32_16x16x32_bf16(ap, bvv[n], oa[m][n],0,0,0);
            }
        }

        // ---- stage o (overlay p, same-wave ordering) then coalesced copy ----
        #pragma unroll
        for (int m=0;m<4;m++)
            #pragma unroll
            for (int n=0;n<3;n++)
                #pragma unroll
                for (int r=0;r<4;r++)
                    pl[(m*16+kg*4+r)*72 + n*16+lx] = __float2bfloat16(oa[m][n][r]);

        #pragma unroll
        for (int i=0;i<12;i++) {
            int flat = i*64 + lane;        // 768 ushort4 chunks = 64 t x 12
            int t  = flat / 12;
            int dd0 = (flat - t*12)*4;
            *(ushort4*)&o_ws[((size_t)(qw*64+t))*192 + h*48 + dd0] =
                *(const ushort4*)&pl[t*72 + dd0];
        }
    }
}

// ---------------------------------------------------------------------------
// K1c: fused proj + residual out-write + GLU + g-write. Block = 1 window.
// ---------------------------------------------------------------------------
__global__ __launch_bounds__(256, 3)
void pg_kernel(const __hip_bfloat16* __restrict__ o_ws, const float* __restrict__ x,
               const __hip_bfloat16* __restrict__ pw, const float* __restrict__ proj_b,
               const __hip_bfloat16* __restrict__ w1b, const float* __restrict__ w1_b,
               __hip_bfloat16* __restrict__ g_ws, float* __restrict__ out, int win0)
{
    __shared__ __align__(16) __hip_bfloat16 ob[64][200];

    const int tid  = threadIdx.x;
    const int lane = tid & 63;
    const int wv   = tid >> 6;
    const int lx   = lane & 15;
    const int kg   = lane >> 4;

    const int qw  = blockIdx.x;
    const int wid = win0 + qw;
    const int b   = wid / 576;
    const int wr  = wid - b*576;
    const int wi  = wr / 24;
    const int wj  = wr - wi*24;

    const __hip_bfloat16* orow = o_ws + (size_t)qw*64*192;

    // ---- proj GEMM: D[oc][t], A=pw[oc][192], B=o[t][192] ----
    f32x4 pa[3][4];
    #pragma unroll
    for (int m=0;m<3;m++)
        #pragma unroll
        for (int n=0;n<4;n++) pa[m][n] = (f32x4){0.f,0.f,0.f,0.f};

    #pragma unroll
    for (int kc=0; kc<6; ++kc) {
        short8v bo[4];
        #pragma unroll
        for (int n=0;n<4;n++)
            bo[n] = *(const short8v*)&orow[(size_t)(n*16+lx)*192 + kc*32 + kg*8];
        #pragma unroll
        for (int mm=0; mm<3; ++mm) {
            short8v ap = *(const short8v*)
                &pw[(size_t)((wv*3+mm)*16 + lx)*192 + kc*32 + kg*8];
            #pragma unroll
            for (int n=0;n<4;n++)
                pa[mm][n] = __builtin_amdgcn_mfma_f32_16x16x32_bf16(ap, bo[n], pa[mm][n],0,0,0);
        }
    }

    // ---- epilogue1: out = x + proj + pb (fp32 global) + bf16 copy to LDS ----
    const size_t obase = (size_t)b*192*HWSZ + (size_t)(wi*8)*192 + wj*8;
    #pragma unroll
    for (int mm=0; mm<3; ++mm) {
        const int oc0 = (wv*3+mm)*16 + kg*4;
        float pb4[4];
        #pragma unroll
        for (int r=0;r<4;r++) pb4[r] = proj_b[oc0+r];
        #pragma unroll
        for (int n=0;n<4;n++) {
            const int t = n*16 + lx;
            const size_t po = (size_t)(t>>3)*192 + (t&7);
            union { ushort4 u; __hip_bfloat16 e[4]; } pk;
            #pragma unroll
            for (int r=0;r<4;r++) {
                const size_t off = obase + (size_t)(oc0+r)*HWSZ + po;
                float v = pa[mm][n][r] + pb4[r] + x[off];
                out[off] = v;
                pk.e[r] = __float2bfloat16(v);
            }
            *(ushort4*)&ob[t][oc0] = pk.u;
        }
    }
    __syncthreads();

    // ---- GLU GEMM: M=384 (a rows 0..191, b rows 192..383), B=ob ----
    f32x4 ga[6][4];
    #pragma unroll
    for (int m=0;m<6;m++)
        #pragma unroll
        for (int n=0;n<4;n++) ga[m][n] = (f32x4){0.f,0.f,0.f,0.f};

    #pragma unroll
    for (int kc=0; kc<6; ++kc) {
        short8v bf[4];
        #pragma unroll
        for (int n=0;n<4;n++)
            bf[n] = *(const short8v*)&ob[n*16+lx][kc*32+kg*8];
        #pragma unroll
        for (int mm=0; mm<6; ++mm) {
            const int m = (mm<3) ? (3*wv+mm) : (12 + 3*wv + mm-3);
            short8v af = *(const short8v*)&w1b[(size_t)(m*16+lx)*192 + kc*32 + kg*8];
            #pragma unroll
            for (int n=0;n<4;n++)
                ga[mm][n] = __builtin_amdgcn_mfma_f32_16x16x32_bf16(af, bf[n], ga[mm][n],0,0,0);
        }
    }
    __syncthreads();   // all ob reads done

    // ---- GLU combine -> reuse ob as g staging ----
    #pragma unroll
    for (int mm=0; mm<3; ++mm) {
        const int oc0 = (3*wv+mm)*16 + kg*4;
        float ba4[4], bb4[4];
        #pragma unroll
        for (int r=0;r<4;r++){ ba4[r] = w1_b[oc0+r]; bb4[r] = w1_b[oc0+r+192]; }
        #pragma unroll
        for (int n=0;n<4;n++) {
            const int t = n*16 + lx;
            union { ushort4 u; __hip_bfloat16 e[4]; } pk;
            #pragma unroll
            for (int r=0;r<4;r++) {
                const float a  = ga[mm][n][r]   + ba4[r];
                const float bv = ga[mm+3][n][r] + bb4[r];
                pk.e[r] = __float2bfloat16(a * (1.f/(1.f+__expf(-bv))));
            }
            *(ushort4*)&ob[t][oc0] = pk.u;
        }
    }
    __syncthreads();

    // ---- coalesced g write (pixel-major, chunk-local image) ----
    const size_t gtile = (size_t)(qw/576)*HWSZ;
    for (int i = tid; i < 1536; i += 256) {
        int t = i / 24, c0 = (i - t*24)*8;
        size_t gaddr = (gtile + (size_t)(wi*8 + (t>>3))*192 + wj*8 + (t&7))*192 + c0;
        *(uint4*)&g_ws[gaddr] = *(const uint4*)&ob[t][c0];
    }
}

// ---------------------------------------------------------------------------
// K3: 3x3 conv via 9-tap shifted MFMA GEMM (R2 structure, chunked images)
// ---------------------------------------------------------------------------
#define KC 32
__global__ __launch_bounds__(256)
void conv_mfma(const __hip_bfloat16* __restrict__ g,
               const __hip_bfloat16* __restrict__ wg,
               const float* __restrict__ w2_b, float* __restrict__ out, int img0)
{
    __shared__ __align__(16) __hip_bfloat16 gt[10*18*32];
    __shared__ __align__(16) __hip_bfloat16 wt[9*96*32];

    int bid = blockIdx.x;
    const int tX = bid % 12; bid /= 12;
    const int tY = bid % 24; bid /= 24;
    const int ob = bid & 1;  bid >>= 1;
    const int bimg_l = bid;
    const int tx0 = tX*16, ty0 = tY*8, oc0 = ob*96;

    const int tid  = threadIdx.x;
    const int lane = tid & 63;
    const int wv   = tid >> 6;
    const int wm   = wv >> 1;
    const int wn   = wv & 1;
    const int lx   = lane & 15;
    const int kg   = lane >> 4;

    f32x4 acc[3][4];
    #pragma unroll
    for (int m=0;m<3;m++)
        #pragma unroll
        for (int n=0;n<4;n++) acc[m][n] = (f32x4){0.f,0.f,0.f,0.f};

    const size_t gbase = (size_t)bimg_l*HWSZ;

    for (int c0 = 0; c0 < 192; c0 += KC) {
        for (int idx = tid; idx < 720; idx += 256) {
            int px = idx >> 2, part = idx & 3;
            int iy = px / 18, ix = px - iy*18;
            int gy = min(max(ty0 + iy - 1, 0), 191);
            int gx = min(max(tx0 + ix - 1, 0), 191);
            *(uint4*)&gt[(iy*18+ix)*32 + part*8] =
                *(const uint4*)&g[(gbase + (size_t)gy*192 + gx)*192 + c0 + part*8];
        }
        for (int idx = tid; idx < 3456; idx += 256) {
            int tap = idx / 384; int rr = idx - tap*384;
            int ocl = rr >> 2, part = rr & 3;
            *(uint4*)&wt[(tap*96+ocl)*32 + part*8] =
                *(const uint4*)&wg[(size_t)tap*36864 + (size_t)(oc0+ocl)*192 + c0 + part*8];
        }
        __syncthreads();

        #pragma unroll
        for (int ky=0; ky<3; ++ky) {
            #pragma unroll
            for (int kx=0; kx<3; ++kx) {
                const int tap = ky*3+kx;
                short8v a[3], bb[4];
                #pragma unroll
                for (int m=0;m<3;m++)
                    a[m] = *(const short8v*)&wt[(tap*96 + wm*48 + m*16 + lx)*32 + kg*8];
                #pragma unroll
                for (int n=0;n<4;n++)
                    bb[n] = *(const short8v*)&gt[((wn*4 + n + ky)*18 + lx + kx)*32 + kg*8];
                #pragma unroll
                for (int m=0;m<3;m++)
                    #pragma unroll
                    for (int n=0;n<4;n++)
                        acc[m][n] = __builtin_amdgcn_mfma_f32_16x16x32_bf16(
                                        a[m], bb[n], acc[m][n], 0, 0, 0);
            }
        }
        __syncthreads();
    }

    #pragma unroll
    for (int m=0;m<3;m++) {
        const int ocb_ = oc0 + wm*48 + m*16 + kg*4;
        #pragma unroll
        for (int n=0;n<4;n++) {
            const int y = ty0 + wn*4 + n;
            const int xx = tx0 + lx;
            #pragma unroll
            for (int r=0;r<4;r++) {
                const int oc = ocb_ + r;
                const size_t o = ((size_t)((img0+bimg_l)*192+oc))*HWSZ + (size_t)y*192 + xx;
                float v = acc[m][n][r] + w2_b[oc];
                v = (v >= 0.f) ? v : 0.2f*v;
                out[o] += v;
            }
        }
    }
}

// ---------------------------------------------------------------------------
extern "C" void kernel_launch(void* const* d_in, const int* in_sizes, int n_in,
                              void* d_out, int out_size, void* d_ws, size_t ws_size,
                              hipStream_t stream)
{
    const float* x        = (const float*)d_in[0];
    const float* qkv_w    = (const float*)d_in[1];
    const float* qkv_b    = (const float*)d_in[2];
    const float* proj_w   = (const float*)d_in[3];
    const float* proj_b   = (const float*)d_in[4];
    const float* bias_tab = (const float*)d_in[5];
    const float* w1_w     = (const float*)d_in[6];
    const float* w1_b     = (const float*)d_in[7];
    const float* w2_w     = (const float*)d_in[8];
    const float* w2_b     = (const float*)d_in[9];
    float* out = (float*)d_out;

    // batch split: s chunks of 8/s images; 4 units (q,k,v,o) of 24576*Q bytes
    int s = 4;
    if      (ws_size >= WBYTES + 4*24576ULL*4608) s = 1;
    else if (ws_size >= WBYTES + 4*24576ULL*2304) s = 2;
    const int Q    = 4608 / s;      // windows per chunk
    const int imgs = 8 / s;         // images per chunk

    char* base = (char*)d_ws;
    __hip_bfloat16* wg  = (__hip_bfloat16*)base;
    __hip_bfloat16* wqp = (__hip_bfloat16*)(base + (size_t)WG_N*2);
    __hip_bfloat16* pwp = (__hip_bfloat16*)(base + (size_t)(WG_N+WQ2_N)*2);
    __hip_bfloat16* w1b = (__hip_bfloat16*)(base + (size_t)(WG_N+WQ2_N+PW2_N)*2);

    const size_t unit = 24576ULL * Q;
    char* up = base + WBYTES;
    __hip_bfloat16* q_ws = (__hip_bfloat16*)(up);
    __hip_bfloat16* k_ws = (__hip_bfloat16*)(up + unit);
    __hip_bfloat16* v_ws = (__hip_bfloat16*)(up + 2*unit);
    __hip_bfloat16* o_ws = (__hip_bfloat16*)(up + 3*unit);
    __hip_bfloat16* g_ws = q_ws;   // overlays q (dead after attn_core)

    prep_weights<<<2160, 256, 0, stream>>>(w2_w, qkv_w, proj_w, w1_w, wg, wqp, pwp, w1b);

    for (int c = 0; c < s; ++c) {
        const int win0 = c * Q;
        qkv_kernel<<<Q,   256, 0, stream>>>(x, wqp, qkv_b, q_ws, k_ws, v_ws, win0);
        attn_core <<<Q/4, 256, 0, stream>>>(q_ws, k_ws, v_ws, bias_tab, o_ws);
        pg_kernel <<<Q,   256, 0, stream>>>(o_ws, x, pwp, proj_b, w1b, w1_b, g_ws, out, win0);
        conv_mfma <<<576*imgs, 256, 0, stream>>>(g_ws, wg, w2_b, out, c*imgs);
    }
}

// Round 6
// 1490.725 us; speedup vs baseline: 1.0393x; 1.0393x over previous
//
#include <hip/hip_runtime.h>
#include <hip/hip_bf16.h>

#define HWSZ (192*192)

typedef __attribute__((ext_vector_type(8))) short short8v;
typedef __attribute__((ext_vector_type(4))) float f32x4;

// prep'd weight element counts
#define WG_N  331776   // conv w: [tap][oc][c]  9*192*192
#define WQ2_N 110592   // qkv  w: [576][192] straight cast
#define PW2_N 36864    // proj w: [192][192] straight cast
#define W1_N  73728    // glu  w: [384][192] straight cast
#define WBYTES ((size_t)2*(WG_N+WQ2_N+PW2_N+W1_N))

// ---------------------------------------------------------------------------
// prep: cast/reorder weights to bf16 (unchanged from R5)
// ---------------------------------------------------------------------------
__global__ __launch_bounds__(256)
void prep_weights(const float* __restrict__ w2_w, const float* __restrict__ qkv_w,
                  const float* __restrict__ proj_w, const float* __restrict__ w1_w,
                  __hip_bfloat16* __restrict__ wg, __hip_bfloat16* __restrict__ wq,
                  __hip_bfloat16* __restrict__ pw, __hip_bfloat16* __restrict__ w1b)
{
    int i = blockIdx.x*256 + threadIdx.x;
    if (i < WG_N) {
        int tap = i / 36864; int r = i - tap*36864;
        int oc = r / 192;    int c = r - oc*192;
        wg[i] = __float2bfloat16(w2_w[((size_t)oc*192 + c)*9 + tap]);
    } else if (i < WG_N + WQ2_N) {
        int j = i - WG_N;  wq[j] = __float2bfloat16(qkv_w[j]);
    } else if (i < WG_N + WQ2_N + PW2_N) {
        int j = i - WG_N - WQ2_N;  pw[j] = __float2bfloat16(proj_w[j]);
    } else if (i < WG_N + WQ2_N + PW2_N + W1_N) {
        int j = i - WG_N - WQ2_N - PW2_N;  w1b[j] = __float2bfloat16(w1_w[j]);
    }
}

// ---------------------------------------------------------------------------
// Fragment layouts (all 16B/lane coalesced; derived from the HW-verified
// convention: A/B-frag lane = (lx = non-K idx, kg*8+0..7 = K), D row=kg*4+r,
// col=lx):
//  Q48/K48 per (win,h): [mt(4)][g(6)][lx(16)][8]   d = g*8   (3072 el)
//  V48     per (win,h): [nd(3)][ktg(8)][lx(16)][8] t = ktg*8 (3072 el)
//  O192    per  win   : [nt(4)][kcg(24)][lx(16)][8] d = kcg*8 (12288 el)
// Pair-token index tp = r*16 + cx  (pixel order, cx in [0,16));
// window token tt: w = cx>>3, tt = r*8 + (cx&7).
// ---------------------------------------------------------------------------

// K1a: QKV GEMM per window-PAIR. Wave = head (M=144 rows). N=128 tokens.
__global__ __launch_bounds__(256, 2)
void qkv_pair(const float* __restrict__ x, const __hip_bfloat16* __restrict__ wq,
              const float* __restrict__ qkv_b,
              __hip_bfloat16* __restrict__ q_ws, __hip_bfloat16* __restrict__ k_ws,
              __hip_bfloat16* __restrict__ v_ws, int b0)
{
    __shared__ __align__(16) __hip_bfloat16 Xs[128][200];
    __shared__ __align__(16) __hip_bfloat16 stg[4][2304];  // per-wave stage

    const int tid = threadIdx.x;
    const int pid = blockIdx.x;
    const int bl  = pid / 288;
    const int rem = pid - bl*288;
    const int wi  = rem / 12;
    const int wjp = rem - wi*12;

    const float* xb = x + ((size_t)(b0+bl)*192)*HWSZ + (size_t)(wi*8)*192 + wjp*16;
    for (int i = tid; i < 24576; i += 256) {
        int c = i >> 7, r2 = i & 127;
        Xs[r2][c] = __float2bfloat16(xb[(size_t)c*HWSZ + (r2>>4)*192 + (r2&15)]);
    }
    __syncthreads();

    const int lane = tid & 63;
    const int h    = tid >> 6;
    const int lx   = lane & 15;
    const int kg   = lane >> 4;

    __hip_bfloat16* S = stg[h];
    const int qbase = bl*576 + wi*24 + wjp*2;   // chunk-local window id (w=0)

    #pragma unroll 1
    for (int reg = 0; reg < 3; ++reg) {
        const int jrow0 = reg*192 + h*48;
        f32x4 qa[3][8];
        #pragma unroll
        for (int m=0;m<3;m++)
            #pragma unroll
            for (int n=0;n<8;n++) qa[m][n] = (f32x4){0.f,0.f,0.f,0.f};

        #pragma unroll
        for (int kc=0; kc<6; ++kc) {
            short8v bf[8];
            #pragma unroll
            for (int n=0;n<8;n++)
                bf[n] = *(const short8v*)&Xs[n*16+lx][kc*32+kg*8];
            #pragma unroll
            for (int mm=0; mm<3; ++mm) {
                short8v af = *(const short8v*)
                    &wq[(size_t)(jrow0 + mm*16 + lx)*192 + kc*32 + kg*8];
                #pragma unroll
                for (int n=0;n<8;n++)
                    qa[mm][n] = __builtin_amdgcn_mfma_f32_16x16x32_bf16(
                                    af, bf[n], qa[mm][n], 0,0,0);
            }
        }

        if (reg < 2) {
            __hip_bfloat16* dst = (reg==0) ? q_ws : k_ws;
            #pragma unroll 1
            for (int mm=0; mm<3; ++mm) {
                float b4[4];
                #pragma unroll
                for (int r=0;r<4;r++) b4[r] = qkv_b[jrow0 + mm*16 + kg*4 + r];
                // stage [tp][16]: dl = kg*4+r
                #pragma unroll
                for (int n=0;n<8;n++) {
                    union { ushort4 u; __hip_bfloat16 e[4]; } pk;
                    #pragma unroll
                    for (int r=0;r<4;r++)
                        pk.e[r] = __float2bfloat16(qa[mm][n][r] + b4[r]);
                    *(ushort4*)&S[(n*16+lx)*16 + kg*4] = pk.u;
                }
                // copy out: kg -> (w, gb); loop mt
                const int w  = kg >> 1;
                const int gb = kg & 1;
                const size_t base = (size_t)((qbase + w)*4 + h)*3072;
                #pragma unroll
                for (int mt=0; mt<4; ++mt) {
                    const int tt = mt*16 + lx;
                    const int tp = (tt>>3)*16 + w*8 + (tt&7);
                    *(uint4*)&dst[base + ((size_t)(mt*6 + mm*2 + gb)*16 + lx)*8] =
                        *(const uint4*)&S[tp*16 + gb*8];
                }
            }
        } else {
            #pragma unroll 1
            for (int mm=0; mm<3; ++mm) {
                float b4[4];
                #pragma unroll
                for (int r=0;r<4;r++) b4[r] = qkv_b[jrow0 + mm*16 + kg*4 + r];
                // stage [dl 16][144]: transposed
                #pragma unroll
                for (int n=0;n<8;n++)
                    #pragma unroll
                    for (int r=0;r<4;r++)
                        S[(kg*4+r)*144 + n*16+lx] =
                            __float2bfloat16(qa[mm][n][r] + b4[r]);
                // copy out: lane lx = d within tile; 4 jobs via (kg, j)
                #pragma unroll
                for (int j=0; j<4; ++j) {
                    const int w   = j >> 1;
                    const int ktg = kg*2 + (j & 1);
                    const size_t base = (size_t)((qbase + w)*4 + h)*3072;
                    *(uint4*)&v_ws[base + ((size_t)(mm*8 + ktg)*16 + lx)*8] =
                        *(const uint4*)&S[lx*144 + ktg*16 + w*8];
                }
            }
        }
    }
}

// ---------------------------------------------------------------------------
// K1b: attention core. Wave = window; 4 windows/block. Fragment-linear IO.
// ---------------------------------------------------------------------------
__global__ __launch_bounds__(256, 3)
void attn_core(const __hip_bfloat16* __restrict__ q_ws,
               const __hip_bfloat16* __restrict__ k_ws,
               const __hip_bfloat16* __restrict__ v_ws,
               const float* __restrict__ bias_tab,
               __hip_bfloat16* __restrict__ o_ws)
{
    __shared__ __align__(16) __hip_bfloat16 p_lds[4][64][72];
    __shared__ __align__(16) __hip_bfloat16 bias_bf[64][66];

    const int tid = threadIdx.x;
    for (int i = tid; i < 4096; i += 256) {
        int tq = i >> 6, tk = i & 63;
        int dy = (tq>>3) - (tk>>3) + 7;
        int dx = (tq&7)  - (tk&7)  + 7;
        bias_bf[tq][tk] = __float2bfloat16(bias_tab[dy*15 + dx]);
    }
    __syncthreads();

    const int lane = tid & 63;
    const int wv   = tid >> 6;
    const int lx   = lane & 15;
    const int kg   = lane >> 4;
    const int qw   = blockIdx.x*4 + wv;

    __hip_bfloat16* pl = &p_lds[wv][0][0];
    const float scale = 0.14433756729740643f; // 1/sqrt(48)
    const short8v z8 = {0,0,0,0,0,0,0,0};
    const size_t obase = (size_t)qw * 12288;

    #pragma unroll 1
    for (int h=0; h<4; ++h) {
        const size_t fb = (size_t)(qw*4 + h)*3072;   // q/k/v frag base

        // ---- scores: K=48 as kc0 (g=kg) + kc1 half-zero (g=4+kg, kg<2) ----
        f32x4 sa[4][4];
        #pragma unroll
        for (int m=0;m<4;m++)
            #pragma unroll
            for (int n=0;n<4;n++) sa[m][n] = (f32x4){0.f,0.f,0.f,0.f};

        {
            short8v bk[4];
            #pragma unroll
            for (int n=0;n<4;n++)
                bk[n] = *(const short8v*)&k_ws[fb + ((size_t)(n*6+kg)*16 + lx)*8];
            #pragma unroll
            for (int m=0;m<4;m++) {
                short8v aq = *(const short8v*)&q_ws[fb + ((size_t)(m*6+kg)*16 + lx)*8];
                #pragma unroll
                for (int n=0;n<4;n++)
                    sa[m][n] = __builtin_amdgcn_mfma_f32_16x16x32_bf16(aq, bk[n], sa[m][n],0,0,0);
            }
        }
        {
            short8v bk[4];
            #pragma unroll
            for (int n=0;n<4;n++) {
                short8v f = z8;
                if (kg < 2) f = *(const short8v*)&k_ws[fb + ((size_t)(n*6+4+kg)*16 + lx)*8];
                bk[n] = f;
            }
            #pragma unroll
            for (int m=0;m<4;m++) {
                short8v aq = z8;
                if (kg < 2) aq = *(const short8v*)&q_ws[fb + ((size_t)(m*6+4+kg)*16 + lx)*8];
                #pragma unroll
                for (int n=0;n<4;n++)
                    sa[m][n] = __builtin_amdgcn_mfma_f32_16x16x32_bf16(aq, bk[n], sa[m][n],0,0,0);
            }
        }

        // ---- softmax -> p_lds ----
        #pragma unroll
        for (int m=0;m<4;m++) {
            #pragma unroll
            for (int r=0;r<4;r++) {
                const int trow = m*16 + kg*4 + r;
                float s[4];
                float mx = -1e30f;
                #pragma unroll
                for (int n=0;n<4;n++){
                    s[n] = sa[m][n][r]*scale + __bfloat162float(bias_bf[trow][n*16+lx]);
                    mx = fmaxf(mx, s[n]);
                }
                mx = fmaxf(mx, __shfl_xor(mx,1));
                mx = fmaxf(mx, __shfl_xor(mx,2));
                mx = fmaxf(mx, __shfl_xor(mx,4));
                mx = fmaxf(mx, __shfl_xor(mx,8));
                float l = 0.f;
                #pragma unroll
                for (int n=0;n<4;n++){ s[n] = __expf(s[n]-mx); l += s[n]; }
                l += __shfl_xor(l,1); l += __shfl_xor(l,2);
                l += __shfl_xor(l,4); l += __shfl_xor(l,8);
                const float inv = 1.f/l;
                #pragma unroll
                for (int n=0;n<4;n++)
                    pl[trow*72 + n*16+lx] = __float2bfloat16(s[n]*inv);
            }
        }

        // ---- PV: K=64 over tk; A=p (LDS), B=V48 frags ----
        f32x4 oa[4][3];
        #pragma unroll
        for (int m=0;m<4;m++)
            #pragma unroll
            for (int n=0;n<3;n++) oa[m][n] = (f32x4){0.f,0.f,0.f,0.f};
        #pragma unroll
        for (int kc=0; kc<2; ++kc) {
            short8v bvv[3];
            #pragma unroll
            for (int n=0;n<3;n++)
                bvv[n] = *(const short8v*)&v_ws[fb + ((size_t)(n*8 + kc*4+kg)*16 + lx)*8];
            #pragma unroll
            for (int m=0;m<4;m++) {
                short8v ap = *(const short8v*)&pl[(m*16+lx)*72 + kc*32 + kg*8];
                #pragma unroll
                for (int n=0;n<3;n++)
                    oa[m][n] = __builtin_amdgcn_mfma_f32_16x16x32_bf16(ap, bvv[n], oa[m][n],0,0,0);
            }
        }

        // ---- stage o per nd (reuse pl; p dead), write O192 frags ----
        #pragma unroll 1
        for (int nd=0; nd<3; ++nd) {
            #pragma unroll
            for (int m=0;m<4;m++)
                #pragma unroll
                for (int r=0;r<4;r++)
                    pl[(m*16 + kg*4 + r)*16 + lx] = __float2bfloat16(oa[m][nd][r]);
            // copy out: nt = kg; dg loop
            #pragma unroll
            for (int dg=0; dg<2; ++dg) {
                *(uint4*)&o_ws[obase + ((size_t)(kg*24 + h*6 + nd*2 + dg)*16 + lx)*8] =
                    *(const uint4*)&pl[(kg*16+lx)*16 + dg*8];
            }
        }
    }
}

// ---------------------------------------------------------------------------
// K1c: fused proj + residual + GLU per window-PAIR (N=128).
// ft token index = w*64 + tt (frag order); pixel loops re-decode for coalescing.
// ---------------------------------------------------------------------------
__global__ __launch_bounds__(256, 2)
void pg_pair(const __hip_bfloat16* __restrict__ o_ws, const float* __restrict__ x,
             const __hip_bfloat16* __restrict__ pw, const float* __restrict__ proj_b,
             const __hip_bfloat16* __restrict__ w1b, const float* __restrict__ w1_b,
             __hip_bfloat16* __restrict__ g_ws, float* __restrict__ out, int b0)
{
    __shared__ __align__(16) __hip_bfloat16 ob[128][200];

    const int tid  = threadIdx.x;
    const int lane = tid & 63;
    const int wv   = tid >> 6;
    const int lx   = lane & 15;
    const int kg   = lane >> 4;

    const int pid = blockIdx.x;
    const int bl  = pid / 288;
    const int rem = pid - bl*288;
    const int wi  = rem / 12;
    const int wjp = rem - wi*12;
    const int qbase = bl*576 + wi*24 + wjp*2;

    // ---- proj GEMM: D[oc][ft], A=pw, B=O192 frags ----
    f32x4 pa[3][8];
    #pragma unroll
    for (int m=0;m<3;m++)
        #pragma unroll
        for (int n=0;n<8;n++) pa[m][n] = (f32x4){0.f,0.f,0.f,0.f};

    #pragma unroll
    for (int kc=0; kc<6; ++kc) {
        short8v bo[8];
        #pragma unroll
        for (int n=0;n<8;n++) {
            const size_t base = (size_t)(qbase + (n>>2)) * 12288;
            bo[n] = *(const short8v*)&o_ws[base + ((size_t)((n&3)*24 + kc*4+kg)*16 + lx)*8];
        }
        #pragma unroll
        for (int mm=0; mm<3; ++mm) {
            short8v ap = *(const short8v*)
                &pw[(size_t)((wv*3+mm)*16 + lx)*192 + kc*32 + kg*8];
            #pragma unroll
            for (int n=0;n<8;n++)
                pa[mm][n] = __builtin_amdgcn_mfma_f32_16x16x32_bf16(ap, bo[n], pa[mm][n],0,0,0);
        }
    }

    // ---- stage proj+pb into ob[ft][oc] ----
    #pragma unroll
    for (int mm=0; mm<3; ++mm) {
        const int oc0 = (wv*3+mm)*16 + kg*4;
        float pb4[4];
        #pragma unroll
        for (int r=0;r<4;r++) pb4[r] = proj_b[oc0+r];
        #pragma unroll
        for (int n=0;n<8;n++) {
            union { ushort4 u; __hip_bfloat16 e[4]; } pk;
            #pragma unroll
            for (int r=0;r<4;r++) pk.e[r] = __float2bfloat16(pa[mm][n][r] + pb4[r]);
            *(ushort4*)&ob[n*16+lx][oc0] = pk.u;
        }
    }
    __syncthreads();

    // ---- out = x + (proj+pb); refresh ob with bf16(out) [pixel-ordered IO] ----
    const size_t obase = ((size_t)(b0+bl)*192)*HWSZ + (size_t)(wi*8)*192 + wjp*16;
    for (int i = tid; i < 24576; i += 256) {
        const int oc = i >> 7, r2 = i & 127;
        const int r = r2 >> 4, cx = r2 & 15;
        const int ft = (cx>>3)*64 + r*8 + (cx&7);
        const size_t off = obase + (size_t)oc*HWSZ + (size_t)r*192 + cx;
        float v = x[off] + __bfloat162float(ob[ft][oc]);
        out[off] = v;
        ob[ft][oc] = __float2bfloat16(v);
    }
    __syncthreads();

    // ---- GLU GEMM: M=384, B=ob ----
    f32x4 ga[6][8];
    #pragma unroll
    for (int m=0;m<6;m++)
        #pragma unroll
        for (int n=0;n<8;n++) ga[m][n] = (f32x4){0.f,0.f,0.f,0.f};

    #pragma unroll
    for (int kc=0; kc<6; ++kc) {
        short8v bf[8];
        #pragma unroll
        for (int n=0;n<8;n++)
            bf[n] = *(const short8v*)&ob[n*16+lx][kc*32+kg*8];
        #pragma unroll
        for (int mm=0; mm<6; ++mm) {
            const int m = (mm<3) ? (3*wv+mm) : (12 + 3*wv + mm-3);
            short8v af = *(const short8v*)&w1b[(size_t)(m*16+lx)*192 + kc*32 + kg*8];
            #pragma unroll
            for (int n=0;n<8;n++)
                ga[mm][n] = __builtin_amdgcn_mfma_f32_16x16x32_bf16(af, bf[n], ga[mm][n],0,0,0);
        }
    }
    __syncthreads();   // all ob reads done

    // ---- GLU combine -> ob = g ----
    #pragma unroll
    for (int mm=0; mm<3; ++mm) {
        const int oc0 = (3*wv+mm)*16 + kg*4;
        float ba4[4], bb4[4];
        #pragma unroll
        for (int r=0;r<4;r++){ ba4[r] = w1_b[oc0+r]; bb4[r] = w1_b[oc0+r+192]; }
        #pragma unroll
        for (int n=0;n<8;n++) {
            union { ushort4 u; __hip_bfloat16 e[4]; } pk;
            #pragma unroll
            for (int r=0;r<4;r++) {
                const float a  = ga[mm][n][r]   + ba4[r];
                const float bv = ga[mm+3][n][r] + bb4[r];
                pk.e[r] = __float2bfloat16(a * (1.f/(1.f+__expf(-bv))));
            }
            *(ushort4*)&ob[n*16+lx][oc0] = pk.u;
        }
    }
    __syncthreads();

    // ---- coalesced g write (pixel-major) ----
    for (int i = tid; i < 3072; i += 256) {
        const int tpix = i / 24, c0 = (i - tpix*24)*8;
        const int r = tpix >> 4, cx = tpix & 15;
        const int ft = (cx>>3)*64 + r*8 + (cx&7);
        const size_t ga_ = ((size_t)bl*HWSZ + (size_t)(wi*8+r)*192 + wjp*16 + cx)*192 + c0;
        *(uint4*)&g_ws[ga_] = *(const uint4*)&ob[ft][c0];
    }
}

// ---------------------------------------------------------------------------
// K3: 3x3 conv via 9-tap shifted MFMA GEMM (unchanged)
// ---------------------------------------------------------------------------
#define KC 32
__global__ __launch_bounds__(256)
void conv_mfma(const __hip_bfloat16* __restrict__ g,
               const __hip_bfloat16* __restrict__ wg,
               const float* __restrict__ w2_b, float* __restrict__ out, int img0)
{
    __shared__ __align__(16) __hip_bfloat16 gt[10*18*32];
    __shared__ __align__(16) __hip_bfloat16 wt[9*96*32];

    int bid = blockIdx.x;
    const int tX = bid % 12; bid /= 12;
    const int tY = bid % 24; bid /= 24;
    const int ob = bid & 1;  bid >>= 1;
    const int bimg_l = bid;
    const int tx0 = tX*16, ty0 = tY*8, oc0 = ob*96;

    const int tid  = threadIdx.x;
    const int lane = tid & 63;
    const int wv   = tid >> 6;
    const int wm   = wv >> 1;
    const int wn   = wv & 1;
    const int lx   = lane & 15;
    const int kg   = lane >> 4;

    f32x4 acc[3][4];
    #pragma unroll
    for (int m=0;m<3;m++)
        #pragma unroll
        for (int n=0;n<4;n++) acc[m][n] = (f32x4){0.f,0.f,0.f,0.f};

    const size_t gbase = (size_t)bimg_l*HWSZ;

    for (int c0 = 0; c0 < 192; c0 += KC) {
        for (int idx = tid; idx < 720; idx += 256) {
            int px = idx >> 2, part = idx & 3;
            int iy = px / 18, ix = px - iy*18;
            int gy = min(max(ty0 + iy - 1, 0), 191);
            int gx = min(max(tx0 + ix - 1, 0), 191);
            *(uint4*)&gt[(iy*18+ix)*32 + part*8] =
                *(const uint4*)&g[(gbase + (size_t)gy*192 + gx)*192 + c0 + part*8];
        }
        for (int idx = tid; idx < 3456; idx += 256) {
            int tap = idx / 384; int rr = idx - tap*384;
            int ocl = rr >> 2, part = rr & 3;
            *(uint4*)&wt[(tap*96+ocl)*32 + part*8] =
                *(const uint4*)&wg[(size_t)tap*36864 + (size_t)(oc0+ocl)*192 + c0 + part*8];
        }
        __syncthreads();

        #pragma unroll
        for (int ky=0; ky<3; ++ky) {
            #pragma unroll
            for (int kx=0; kx<3; ++kx) {
                const int tap = ky*3+kx;
                short8v a[3], bb[4];
                #pragma unroll
                for (int m=0;m<3;m++)
                    a[m] = *(const short8v*)&wt[(tap*96 + wm*48 + m*16 + lx)*32 + kg*8];
                #pragma unroll
                for (int n=0;n<4;n++)
                    bb[n] = *(const short8v*)&gt[((wn*4 + n + ky)*18 + lx + kx)*32 + kg*8];
                #pragma unroll
                for (int m=0;m<3;m++)
                    #pragma unroll
                    for (int n=0;n<4;n++)
                        acc[m][n] = __builtin_amdgcn_mfma_f32_16x16x32_bf16(
                                        a[m], bb[n], acc[m][n], 0, 0, 0);
            }
        }
        __syncthreads();
    }

    #pragma unroll
    for (int m=0;m<3;m++) {
        const int ocb_ = oc0 + wm*48 + m*16 + kg*4;
        #pragma unroll
        for (int n=0;n<4;n++) {
            const int y = ty0 + wn*4 + n;
            const int xx = tx0 + lx;
            #pragma unroll
            for (int r=0;r<4;r++) {
                const int oc = ocb_ + r;
                const size_t o = ((size_t)((img0+bimg_l)*192+oc))*HWSZ + (size_t)y*192 + xx;
                float v = acc[m][n][r] + w2_b[oc];
                v = (v >= 0.f) ? v : 0.2f*v;
                out[o] += v;
            }
        }
    }
}

// ---------------------------------------------------------------------------
extern "C" void kernel_launch(void* const* d_in, const int* in_sizes, int n_in,
                              void* d_out, int out_size, void* d_ws, size_t ws_size,
                              hipStream_t stream)
{
    const float* x        = (const float*)d_in[0];
    const float* qkv_w    = (const float*)d_in[1];
    const float* qkv_b    = (const float*)d_in[2];
    const float* proj_w   = (const float*)d_in[3];
    const float* proj_b   = (const float*)d_in[4];
    const float* bias_tab = (const float*)d_in[5];
    const float* w1_w     = (const float*)d_in[6];
    const float* w1_b     = (const float*)d_in[7];
    const float* w2_w     = (const float*)d_in[8];
    const float* w2_b     = (const float*)d_in[9];
    float* out = (float*)d_out;

    int s = 4;
    if      (ws_size >= WBYTES + 4*24576ULL*4608) s = 1;
    else if (ws_size >= WBYTES + 4*24576ULL*2304) s = 2;
    const int Q    = 4608 / s;
    const int imgs = 8 / s;

    char* base = (char*)d_ws;
    __hip_bfloat16* wg  = (__hip_bfloat16*)base;
    __hip_bfloat16* wqp = (__hip_bfloat16*)(base + (size_t)WG_N*2);
    __hip_bfloat16* pwp = (__hip_bfloat16*)(base + (size_t)(WG_N+WQ2_N)*2);
    __hip_bfloat16* w1b = (__hip_bfloat16*)(base + (size_t)(WG_N+WQ2_N+PW2_N)*2);

    const size_t unit = 24576ULL * Q;
    char* up = base + WBYTES;
    __hip_bfloat16* q_ws = (__hip_bfloat16*)(up);
    __hip_bfloat16* k_ws = (__hip_bfloat16*)(up + unit);
    __hip_bfloat16* v_ws = (__hip_bfloat16*)(up + 2*unit);
    __hip_bfloat16* o_ws = (__hip_bfloat16*)(up + 3*unit);
    __hip_bfloat16* g_ws = q_ws;   // overlays q (dead after attn_core)

    prep_weights<<<2160, 256, 0, stream>>>(w2_w, qkv_w, proj_w, w1_w, wg, wqp, pwp, w1b);

    for (int c = 0; c < s; ++c) {
        const int b0 = c * imgs;
        qkv_pair <<<Q/2, 256, 0, stream>>>(x, wqp, qkv_b, q_ws, k_ws, v_ws, b0);
        attn_core<<<Q/4, 256, 0, stream>>>(q_ws, k_ws, v_ws, bias_tab, o_ws);
        pg_pair  <<<Q/2, 256, 0, stream>>>(o_ws, x, pwp, proj_b, w1b, w1_b, g_ws, out, b0);
        conv_mfma<<<576*imgs, 256, 0, stream>>>(g_ws, wg, w2_b, out, b0);
    }
}

// Round 7
// 851.484 us; speedup vs baseline: 1.8196x; 1.7507x over previous
//
#include <hip/hip_runtime.h>
#include <hip/hip_bf16.h>

#define HWSZ (192*192)

typedef __attribute__((ext_vector_type(8))) short short8v;
typedef __attribute__((ext_vector_type(4))) float f32x4;

// prep'd weight element counts
#define WG_N  331776   // conv w: [tap][oc][c]  9*192*192
#define WQ2_N 110592   // qkv  w: [576][192] straight cast
#define PW2_N 36864    // proj w: [192][192] straight cast
#define W1_N  73728    // glu  w: [384][192] straight cast
#define WBYTES ((size_t)2*(WG_N+WQ2_N+PW2_N+W1_N))

// ---------------------------------------------------------------------------
// prep: cast/reorder weights to bf16
// ---------------------------------------------------------------------------
__global__ __launch_bounds__(256)
void prep_weights(const float* __restrict__ w2_w, const float* __restrict__ qkv_w,
                  const float* __restrict__ proj_w, const float* __restrict__ w1_w,
                  __hip_bfloat16* __restrict__ wg, __hip_bfloat16* __restrict__ wq,
                  __hip_bfloat16* __restrict__ pw, __hip_bfloat16* __restrict__ w1b)
{
    int i = blockIdx.x*256 + threadIdx.x;
    if (i < WG_N) {
        int tap = i / 36864; int r = i - tap*36864;
        int oc = r / 192;    int c = r - oc*192;
        wg[i] = __float2bfloat16(w2_w[((size_t)oc*192 + c)*9 + tap]);
    } else if (i < WG_N + WQ2_N) {
        int j = i - WG_N;  wq[j] = __float2bfloat16(qkv_w[j]);
    } else if (i < WG_N + WQ2_N + PW2_N) {
        int j = i - WG_N - WQ2_N;  pw[j] = __float2bfloat16(proj_w[j]);
    } else if (i < WG_N + WQ2_N + PW2_N + W1_N) {
        int j = i - WG_N - WQ2_N - PW2_N;  w1b[j] = __float2bfloat16(w1_w[j]);
    }
}

// ---------------------------------------------------------------------------
// Fused window kernel: QKV -> scores+bias -> softmax -> PV -> proj(+residual)
// -> GLU -> g.  One block per window; wave = head.  No global intermediates.
// Fragment convention (HW-verified R2-R6):
//   A/B-frag: lane(kg,lx): element [non-K = lx][k = kg*8 + j], j contiguous
//   D:        lane(kg,lx): [row = kg*4 + r][col = lx]
// D->frag conversions go through a 4.5KB per-wave LDS scratch in half-passes.
// LDS: Xs 25.6K + Os 25.6K + scr 18.4K + bias 8.4K = 76.3KB -> 2 blocks/CU.
// ---------------------------------------------------------------------------
__global__ __launch_bounds__(256, 2)
void wac_fused(const float* __restrict__ x,
               const __hip_bfloat16* __restrict__ wq, const float* __restrict__ qkv_b,
               const __hip_bfloat16* __restrict__ pw, const float* __restrict__ proj_b,
               const __hip_bfloat16* __restrict__ w1b, const float* __restrict__ w1_b,
               const float* __restrict__ bias_tab,
               __hip_bfloat16* __restrict__ g_ws, float* __restrict__ out)
{
    __shared__ __align__(16) __hip_bfloat16 Xs[64][200];   // bf16 x; later g stage
    __shared__ __align__(16) __hip_bfloat16 Os[64][200];   // O heads; later out stage
    __shared__ __align__(16) __hip_bfloat16 scr[4][2304];  // per-wave D->frag scratch
    __shared__ __align__(16) __hip_bfloat16 bias_bf[64][66];

    const int tid = threadIdx.x;
    // XCD swizzle: blocks n%8==k handle image k's windows -> x locality per XCD
    const int wid = (blockIdx.x & 7)*576 + (blockIdx.x >> 3);
    const int img = wid / 576;
    const int wr  = wid - img*576;
    const int wi  = wr / 24;
    const int wj  = wr - wi*24;

    const float* xb = x + (size_t)img*192*HWSZ + (size_t)(wi*8)*192 + wj*8;
    for (int i = tid; i < 12288; i += 256) {
        int c = i >> 6, t = i & 63;
        Xs[t][c] = __float2bfloat16(xb[(size_t)c*HWSZ + (t>>3)*192 + (t&7)]);
    }
    for (int i = tid; i < 4096; i += 256) {
        int tq = i >> 6, tk = i & 63;
        bias_bf[tq][tk] = __float2bfloat16(
            bias_tab[((tq>>3)-(tk>>3)+7)*15 + ((tq&7)-(tk&7)+7)]);
    }
    __syncthreads();                                      // B1

    const int lane = tid & 63;
    const int wv   = tid >> 6;        // wave = head
    const int lx   = lane & 15;
    const int kg   = lane >> 4;
    __hip_bfloat16* S = scr[wv];
    const short8v z8 = {0,0,0,0,0,0,0,0};
    const float scale = 0.14433756729740643f; // 1/sqrt(48)

    // ---------------- QKV for head wv (q->A-frags, k/v->B-frags) ----------
    short8v qAf[4][2], kBf[4][2], vBf[3][2];
    #pragma unroll
    for (int reg = 0; reg < 3; ++reg) {
        const int jrow0 = reg*192 + wv*48;
        f32x4 qa[3][4];
        #pragma unroll
        for (int m=0;m<3;m++)
            #pragma unroll
            for (int n=0;n<4;n++) qa[m][n] = (f32x4){0.f,0.f,0.f,0.f};

        #pragma unroll
        for (int kc=0; kc<6; ++kc) {
            short8v bfX[4];
            #pragma unroll
            for (int n=0;n<4;n++)
                bfX[n] = *(const short8v*)&Xs[n*16+lx][kc*32+kg*8];
            #pragma unroll
            for (int mm=0; mm<3; ++mm) {
                short8v af = *(const short8v*)
                    &wq[(size_t)(jrow0 + mm*16 + lx)*192 + kc*32 + kg*8];
                #pragma unroll
                for (int n=0;n<4;n++)
                    qa[mm][n] = __builtin_amdgcn_mfma_f32_16x16x32_bf16(
                                    af, bfX[n], qa[mm][n], 0,0,0);
            }
        }
        float b4[3][4];
        #pragma unroll
        for (int mm=0;mm<3;mm++)
            #pragma unroll
            for (int r=0;r<4;r++) b4[mm][r] = qkv_b[jrow0 + mm*16 + kg*4 + r];

        if (reg < 2) {
            // two half-passes over t: write [32][56] (rows t-local, cols d), read frags
            #pragma unroll
            for (int hp=0; hp<2; ++hp) {
                #pragma unroll
                for (int mm=0;mm<3;mm++)
                    #pragma unroll
                    for (int nl=0;nl<2;nl++)
                        #pragma unroll
                        for (int r=0;r<4;r++)
                            S[(nl*16+lx)*56 + mm*16+kg*4+r] =
                                __float2bfloat16(qa[mm][hp*2+nl][r] + b4[mm][r]);
                #pragma unroll
                for (int mtl=0; mtl<2; ++mtl) {
                    short8v f0 = *(const short8v*)&S[(mtl*16+lx)*56 + kg*8];
                    short8v f1 = (kg<2) ? *(const short8v*)&S[(mtl*16+lx)*56 + 32 + kg*8] : z8;
                    if (reg==0) { qAf[hp*2+mtl][0]=f0; qAf[hp*2+mtl][1]=f1; }
                    else        { kBf[hp*2+mtl][0]=f0; kBf[hp*2+mtl][1]=f1; }
                }
            }
        } else {
            // v: three passes over d-tiles: write [16][72] (rows d-local, cols t)
            #pragma unroll
            for (int mm=0;mm<3;mm++) {
                #pragma unroll
                for (int n=0;n<4;n++)
                    #pragma unroll
                    for (int r=0;r<4;r++)
                        S[(kg*4+r)*72 + n*16+lx] =
                            __float2bfloat16(qa[mm][n][r] + b4[mm][r]);
                vBf[mm][0] = *(const short8v*)&S[lx*72 + kg*8];
                vBf[mm][1] = *(const short8v*)&S[lx*72 + 32 + kg*8];
            }
        }
    }

    // ---------------- scores (K=48: kc1 half-zero) ----------------
    f32x4 sa[4][4];
    #pragma unroll
    for (int m=0;m<4;m++)
        #pragma unroll
        for (int n=0;n<4;n++) sa[m][n] = (f32x4){0.f,0.f,0.f,0.f};
    #pragma unroll
    for (int kc2=0; kc2<2; ++kc2)
        #pragma unroll
        for (int m=0;m<4;m++)
            #pragma unroll
            for (int n=0;n<4;n++)
                sa[m][n] = __builtin_amdgcn_mfma_f32_16x16x32_bf16(
                               qAf[m][kc2], kBf[n][kc2], sa[m][n], 0,0,0);

    // ---------------- softmax + PV per 32-row half ----------------
    #pragma unroll
    for (int hp=0; hp<2; ++hp) {
        #pragma unroll
        for (int ml=0; ml<2; ++ml) {
            const int m = hp*2 + ml;
            #pragma unroll
            for (int r=0;r<4;r++) {
                const int trow = m*16 + kg*4 + r;
                float s[4];
                float mx = -1e30f;
                #pragma unroll
                for (int n=0;n<4;n++){
                    s[n] = sa[m][n][r]*scale + __bfloat162float(bias_bf[trow][n*16+lx]);
                    mx = fmaxf(mx, s[n]);
                }
                mx = fmaxf(mx, __shfl_xor(mx,1));
                mx = fmaxf(mx, __shfl_xor(mx,2));
                mx = fmaxf(mx, __shfl_xor(mx,4));
                mx = fmaxf(mx, __shfl_xor(mx,8));
                float l = 0.f;
                #pragma unroll
                for (int n=0;n<4;n++){ s[n] = __expf(s[n]-mx); l += s[n]; }
                l += __shfl_xor(l,1); l += __shfl_xor(l,2);
                l += __shfl_xor(l,4); l += __shfl_xor(l,8);
                const float inv = 1.f/l;
                #pragma unroll
                for (int n=0;n<4;n++)
                    S[(ml*16+kg*4+r)*72 + n*16+lx] = __float2bfloat16(s[n]*inv);
            }
        }
        short8v pA[2][2];
        #pragma unroll
        for (int ml=0; ml<2; ++ml) {
            pA[ml][0] = *(const short8v*)&S[(ml*16+lx)*72 + kg*8];
            pA[ml][1] = *(const short8v*)&S[(ml*16+lx)*72 + 32 + kg*8];
        }
        f32x4 oa[2][3];
        #pragma unroll
        for (int ml=0;ml<2;ml++)
            #pragma unroll
            for (int n=0;n<3;n++) oa[ml][n] = (f32x4){0.f,0.f,0.f,0.f};
        #pragma unroll
        for (int kc2=0; kc2<2; ++kc2)
            #pragma unroll
            for (int ml=0;ml<2;ml++)
                #pragma unroll
                for (int n=0;n<3;n++)
                    oa[ml][n] = __builtin_amdgcn_mfma_f32_16x16x32_bf16(
                                    pA[ml][kc2], vBf[n][kc2], oa[ml][n], 0,0,0);
        #pragma unroll
        for (int ml=0;ml<2;ml++)
            #pragma unroll
            for (int n=0;n<3;n++)
                #pragma unroll
                for (int r=0;r<4;r++)
                    Os[(hp*2+ml)*16+kg*4+r][wv*48 + n*16+lx] =
                        __float2bfloat16(oa[ml][n][r]);
    }
    __syncthreads();                                      // B2: O complete

    // ---------------- proj (wave = 48 oc rows) + residual ----------------
    f32x4 pa[3][4];
    #pragma unroll
    for (int m=0;m<3;m++)
        #pragma unroll
        for (int n=0;n<4;n++) pa[m][n] = (f32x4){0.f,0.f,0.f,0.f};
    #pragma unroll
    for (int kc=0; kc<6; ++kc) {
        short8v bo[4];
        #pragma unroll
        for (int n=0;n<4;n++)
            bo[n] = *(const short8v*)&Os[n*16+lx][kc*32+kg*8];
        #pragma unroll
        for (int mm=0; mm<3; ++mm) {
            short8v ap = *(const short8v*)
                &pw[(size_t)(wv*48 + mm*16 + lx)*192 + kc*32 + kg*8];
            #pragma unroll
            for (int n=0;n<4;n++)
                pa[mm][n] = __builtin_amdgcn_mfma_f32_16x16x32_bf16(
                                ap, bo[n], pa[mm][n], 0,0,0);
        }
    }
    // out = bf16(x) + proj + pb; write global; keep values for staging
    const size_t obase = (size_t)img*192*HWSZ + (size_t)(wi*8)*192 + wj*8;
    #pragma unroll
    for (int mm=0; mm<3; ++mm) {
        const int oc0 = wv*48 + mm*16 + kg*4;
        float pb4[4];
        #pragma unroll
        for (int r=0;r<4;r++) pb4[r] = proj_b[oc0+r];
        #pragma unroll
        for (int n=0;n<4;n++) {
            const int t = n*16 + lx;
            const size_t po = (size_t)(t>>3)*192 + (t&7);
            #pragma unroll
            for (int r=0;r<4;r++) {
                float v = pa[mm][n][r] + pb4[r] + __bfloat162float(Xs[t][oc0+r]);
                pa[mm][n][r] = v;
                out[obase + (size_t)(oc0+r)*HWSZ + po] = v;
            }
        }
    }
    __syncthreads();                                      // B3: O reads done
    #pragma unroll
    for (int mm=0; mm<3; ++mm) {
        const int oc0 = wv*48 + mm*16 + kg*4;
        #pragma unroll
        for (int n=0;n<4;n++) {
            const int t = n*16 + lx;
            union { ushort4 u; __hip_bfloat16 e[4]; } pk;
            #pragma unroll
            for (int r=0;r<4;r++) pk.e[r] = __float2bfloat16(pa[mm][n][r]);
            *(ushort4*)&Os[t][oc0] = pk.u;
        }
    }
    __syncthreads();                                      // B4: out stage ready

    // ---------------- GLU (wave = 96 rows: paired a/b tiles) ----------------
    f32x4 ga[6][4];
    #pragma unroll
    for (int m=0;m<6;m++)
        #pragma unroll
        for (int n=0;n<4;n++) ga[m][n] = (f32x4){0.f,0.f,0.f,0.f};
    #pragma unroll
    for (int kc=0; kc<6; ++kc) {
        short8v bf2[4];
        #pragma unroll
        for (int n=0;n<4;n++)
            bf2[n] = *(const short8v*)&Os[n*16+lx][kc*32+kg*8];
        #pragma unroll
        for (int mm=0; mm<6; ++mm) {
            const int mrow = ((mm<3) ? (3*wv+mm) : (12 + 3*wv + mm-3))*16 + lx;
            short8v af = *(const short8v*)&w1b[(size_t)mrow*192 + kc*32 + kg*8];
            #pragma unroll
            for (int n=0;n<4;n++)
                ga[mm][n] = __builtin_amdgcn_mfma_f32_16x16x32_bf16(
                                af, bf2[n], ga[mm][n], 0,0,0);
        }
    }
    // GLU combine -> stage g into Xs (dead after residual)
    #pragma unroll
    for (int mm=0; mm<3; ++mm) {
        const int oc0 = (3*wv+mm)*16 + kg*4;
        float ba4[4], bb4[4];
        #pragma unroll
        for (int r=0;r<4;r++){ ba4[r] = w1_b[oc0+r]; bb4[r] = w1_b[oc0+r+192]; }
        #pragma unroll
        for (int n=0;n<4;n++) {
            union { ushort4 u; __hip_bfloat16 e[4]; } pk;
            #pragma unroll
            for (int r=0;r<4;r++) {
                const float a  = ga[mm][n][r]   + ba4[r];
                const float bv = ga[mm+3][n][r] + bb4[r];
                pk.e[r] = __float2bfloat16(a * (1.f/(1.f+__expf(-bv))));
            }
            *(ushort4*)&Xs[n*16+lx][oc0] = pk.u;
        }
    }
    __syncthreads();                                      // B5: g stage ready

    // coalesced g write (pixel-major [img][y][x][c])
    for (int i = tid; i < 1536; i += 256) {
        const int t = i / 24, c0 = (i - t*24)*8;
        const size_t ga_ = ((size_t)img*HWSZ +
                            (size_t)(wi*8 + (t>>3))*192 + wj*8 + (t&7))*192 + c0;
        *(uint4*)&g_ws[ga_] = *(const uint4*)&Xs[t][c0];
    }
}

// ---------------------------------------------------------------------------
// K3: 3x3 conv via 9-tap shifted MFMA GEMM (unchanged)
// ---------------------------------------------------------------------------
#define KC 32
__global__ __launch_bounds__(256)
void conv_mfma(const __hip_bfloat16* __restrict__ g,
               const __hip_bfloat16* __restrict__ wg,
               const float* __restrict__ w2_b, float* __restrict__ out, int img0)
{
    __shared__ __align__(16) __hip_bfloat16 gt[10*18*32];
    __shared__ __align__(16) __hip_bfloat16 wt[9*96*32];

    int bid = blockIdx.x;
    const int tX = bid % 12; bid /= 12;
    const int tY = bid % 24; bid /= 24;
    const int ob = bid & 1;  bid >>= 1;
    const int bimg_l = bid;
    const int tx0 = tX*16, ty0 = tY*8, oc0 = ob*96;

    const int tid  = threadIdx.x;
    const int lane = tid & 63;
    const int wv   = tid >> 6;
    const int wm   = wv >> 1;
    const int wn   = wv & 1;
    const int lx   = lane & 15;
    const int kg   = lane >> 4;

    f32x4 acc[3][4];
    #pragma unroll
    for (int m=0;m<3;m++)
        #pragma unroll
        for (int n=0;n<4;n++) acc[m][n] = (f32x4){0.f,0.f,0.f,0.f};

    const size_t gbase = (size_t)bimg_l*HWSZ;

    for (int c0 = 0; c0 < 192; c0 += KC) {
        for (int idx = tid; idx < 720; idx += 256) {
            int px = idx >> 2, part = idx & 3;
            int iy = px / 18, ix = px - iy*18;
            int gy = min(max(ty0 + iy - 1, 0), 191);
            int gx = min(max(tx0 + ix - 1, 0), 191);
            *(uint4*)&gt[(iy*18+ix)*32 + part*8] =
                *(const uint4*)&g[(gbase + (size_t)gy*192 + gx)*192 + c0 + part*8];
        }
        for (int idx = tid; idx < 3456; idx += 256) {
            int tap = idx / 384; int rr = idx - tap*384;
            int ocl = rr >> 2, part = rr & 3;
            *(uint4*)&wt[(tap*96+ocl)*32 + part*8] =
                *(const uint4*)&wg[(size_t)tap*36864 + (size_t)(oc0+ocl)*192 + c0 + part*8];
        }
        __syncthreads();

        #pragma unroll
        for (int ky=0; ky<3; ++ky) {
            #pragma unroll
            for (int kx=0; kx<3; ++kx) {
                const int tap = ky*3+kx;
                short8v a[3], bb[4];
                #pragma unroll
                for (int m=0;m<3;m++)
                    a[m] = *(const short8v*)&wt[(tap*96 + wm*48 + m*16 + lx)*32 + kg*8];
                #pragma unroll
                for (int n=0;n<4;n++)
                    bb[n] = *(const short8v*)&gt[((wn*4 + n + ky)*18 + lx + kx)*32 + kg*8];
                #pragma unroll
                for (int m=0;m<3;m++)
                    #pragma unroll
                    for (int n=0;n<4;n++)
                        acc[m][n] = __builtin_amdgcn_mfma_f32_16x16x32_bf16(
                                        a[m], bb[n], acc[m][n], 0, 0, 0);
            }
        }
        __syncthreads();
    }

    #pragma unroll
    for (int m=0;m<3;m++) {
        const int ocb_ = oc0 + wm*48 + m*16 + kg*4;
        #pragma unroll
        for (int n=0;n<4;n++) {
            const int y = ty0 + wn*4 + n;
            const int xx = tx0 + lx;
            #pragma unroll
            for (int r=0;r<4;r++) {
                const int oc = ocb_ + r;
                const size_t o = ((size_t)((img0+bimg_l)*192+oc))*HWSZ + (size_t)y*192 + xx;
                float v = acc[m][n][r] + w2_b[oc];
                v = (v >= 0.f) ? v : 0.2f*v;
                out[o] += v;
            }
        }
    }
}

// ---------------------------------------------------------------------------
extern "C" void kernel_launch(void* const* d_in, const int* in_sizes, int n_in,
                              void* d_out, int out_size, void* d_ws, size_t ws_size,
                              hipStream_t stream)
{
    const float* x        = (const float*)d_in[0];
    const float* qkv_w    = (const float*)d_in[1];
    const float* qkv_b    = (const float*)d_in[2];
    const float* proj_w   = (const float*)d_in[3];
    const float* proj_b   = (const float*)d_in[4];
    const float* bias_tab = (const float*)d_in[5];
    const float* w1_w     = (const float*)d_in[6];
    const float* w1_b     = (const float*)d_in[7];
    const float* w2_w     = (const float*)d_in[8];
    const float* w2_b     = (const float*)d_in[9];
    float* out = (float*)d_out;

    char* base = (char*)d_ws;
    __hip_bfloat16* wg  = (__hip_bfloat16*)base;
    __hip_bfloat16* wqp = (__hip_bfloat16*)(base + (size_t)WG_N*2);
    __hip_bfloat16* pwp = (__hip_bfloat16*)(base + (size_t)(WG_N+WQ2_N)*2);
    __hip_bfloat16* w1b = (__hip_bfloat16*)(base + (size_t)(WG_N+WQ2_N+PW2_N)*2);
    __hip_bfloat16* g_ws = (__hip_bfloat16*)(base + WBYTES);   // 113.2 MB

    prep_weights<<<2160, 256, 0, stream>>>(w2_w, qkv_w, proj_w, w1_w, wg, wqp, pwp, w1b);
    wac_fused   <<<4608, 256, 0, stream>>>(x, wqp, qkv_b, pwp, proj_b, w1b, w1_b,
                                           bias_tab, g_ws, out);
    conv_mfma   <<<4608, 256, 0, stream>>>(g_ws, wg, w2_b, out, 0);
}